// Round 15
// baseline (609.576 us; speedup 1.0000x reference)
//
#include <hip/hip_runtime.h>

#define D0c 40
#define D1c 40
#define D2c 20
#define NVOX 128000

typedef __attribute__((ext_vector_type(4))) float f4;
typedef __attribute__((ext_vector_type(8))) __bf16 bf8;
typedef __attribute__((ext_vector_type(8))) unsigned short u8s;

static __device__ __forceinline__ unsigned short f2bf(float f) {
  union { float f; unsigned int u; } v; v.f = f;
  unsigned int r = v.u + 0x7fffu + ((v.u >> 16) & 1u);
  return (unsigned short)(r >> 16);
}
static __device__ __forceinline__ float bf2f(unsigned short h) {
  union { unsigned int u; float f; } v; v.u = ((unsigned int)h) << 16;
  return v.f;
}

#define MFMA16(a, b, c) __builtin_amdgcn_mfma_f32_16x16x32_bf16((a), (b), (c), 0, 0, 0)

static __device__ __forceinline__ void gload16(const void* g, void* l) {
  __builtin_amdgcn_global_load_lds((const __attribute__((address_space(1))) unsigned int*)g,
                                   (__attribute__((address_space(3))) unsigned int*)l, 16, 0, 0);
}

// ---- fused row-pair conv helpers (weights read ONCE per pair of z-rows) ----
// requires in scope: base[9], zpad, ch0 (channel byte base), wl, P,Q,R,S
#define PLOADR(NB, RR)                                                        \
  do {                                                                        \
    _Pragma("unroll") for (int c = 0; c < 9; c++) {                           \
      const unsigned short* p_ = ((RR) >= 0 && (RR) < 20)                     \
          ? (base[c] + (size_t)(RR) * 256) : (zpad + ch0);                    \
      NB[c] = *(const ushort4*)p_;                                            \
    }                                                                         \
  } while (0)

#define PAIR_BODY(N0, N1)                                                     \
  do {                                                                        \
    _Pragma("unroll") for (int c = 0; c < 9; c++) {                           \
      f4 cA, cB;                                                              \
      cA.x = bf2f(N0[c].x); cA.y = bf2f(N0[c].y);                             \
      cA.z = bf2f(N0[c].z); cA.w = bf2f(N0[c].w);                             \
      cB.x = bf2f(N1[c].x); cB.y = bf2f(N1[c].y);                             \
      cB.z = bf2f(N1[c].z); cB.w = bf2f(N1[c].w);                             \
      const f4 w0 = *(const f4*)&wl[(c * 3 + 0) * 256 + ch0];                 \
      const f4 w1 = *(const f4*)&wl[(c * 3 + 1) * 256 + ch0];                 \
      const f4 w2 = *(const f4*)&wl[(c * 3 + 2) * 256 + ch0];                 \
      P += w2 * cA;                                                           \
      Q += w1 * cA; Q += w2 * cB;                                             \
      R += w0 * cA; R += w1 * cB;                                             \
      S += w0 * cB;                                                           \
      if (c == 4) { Q += cA; R += cB; }                                       \
    }                                                                         \
  } while (0)

#define PAIR_SHIFT()                                                          \
  do { P = R; Q = S; R = (f4){0.f,0.f,0.f,0.f}; S = (f4){0.f,0.f,0.f,0.f}; } while (0)

// ---------------------------------------------------------------- weight prep (+ zero page)
__global__ __launch_bounds__(256) void k_prepw(const float* __restrict__ qkv_w,
                                               const float* __restrict__ proj_w,
                                               unsigned short* __restrict__ wq,
                                               unsigned short* __restrict__ wp,
                                               unsigned short* __restrict__ zpad) {
  if (blockIdx.x == 1024) {
    u8s z = {0, 0, 0, 0, 0, 0, 0, 0};
    for (int i = threadIdx.x; i < 768; i += 256) *(u8s*)(zpad + i * 8) = z;
    return;
  }
  int id = blockIdx.x * 256 + threadIdx.x;
  if (id < 768 * 256) {
    int kk = id & 31, row = (id >> 5) & 127, kc = (id >> 12) & 7, nt = id >> 15;
    int s = kk >> 3, kj = kk & 7;
    int g = s ^ ((row >> 1) & 3);
    int k = kc * 32 + g * 8 + kj;
    int n = nt * 128 + row;
    wq[id] = f2bf(qkv_w[k * 768 + n]);
  } else {
    int j = id - 768 * 256;
    int kk = j & 31, row = (j >> 5) & 127, kc = (j >> 12) & 7, nt = j >> 15;
    int s = kk >> 3, kj = kk & 7;
    int g = s ^ ((row >> 1) & 3);
    int k = kc * 32 + g * 8 + kj;
    int n = nt * 128 + row;
    wp[j] = f2bf(proj_w[k * 256 + n]);
  }
}

// ---------------------------------------------------------------- rmsnorm (pre)
__global__ __launch_bounds__(256) void k_rms1(const float* __restrict__ x,
                                              const float* __restrict__ w,
                                              unsigned short* __restrict__ xn) {
  int wv = threadIdx.x >> 6, ln = threadIdx.x & 63;
  int n = blockIdx.x * 4 + wv;
  f4 v = ((const f4*)(x + (size_t)n * 256))[ln];
  float ss = v.x * v.x + v.y * v.y + v.z * v.z + v.w * v.w;
#pragma unroll
  for (int m = 32; m >= 1; m >>= 1) ss += __shfl_xor(ss, m);
  float rs = rsqrtf(ss * (1.f / 256.f) + 1e-6f);
  f4 wv4 = ((const f4*)w)[ln];
  ushort4 o;
  o.x = f2bf(v.x * wv4.x * rs); o.y = f2bf(v.y * wv4.y * rs);
  o.z = f2bf(v.z * wv4.z * rs); o.w = f2bf(v.w * wv4.w * rs);
  ((ushort4*)(xn + (size_t)n * 256))[ln] = o;
}

// ---------------------------------------------------------------- dwconv pre: fused row-pair, zero-page, pair-deep prefetch
__global__ __launch_bounds__(256) void k_convpre(const unsigned short* __restrict__ xn,
                                                 const float* __restrict__ dw,
                                                 const unsigned short* __restrict__ zpad,
                                                 unsigned short* __restrict__ xin) {
  __shared__ float wl[6912];
  for (int i = threadIdx.x; i < 6912; i += 256) wl[i] = dw[i];
  __syncthreads();
  int wv = threadIdx.x >> 6, ln = threadIdx.x & 63;
  int col = blockIdx.x * 4 + wv;
  int z1 = col % D1c; int t = col / D1c; int z0 = t % D0c; int b = t / D0c;
  int ch0 = ln * 4;

  const unsigned short* base[9];
#pragma unroll
  for (int c = 0; c < 9; c++) {
    int dy = c / 3 - 1, dx = c % 3 - 1;
    int y0 = z0 + dy, y1 = z1 + dx;
    bool valid = ((unsigned)y0 < (unsigned)D0c) && ((unsigned)y1 < (unsigned)D1c);
    base[c] = valid ? (xn + ((size_t)((b * D0c + y0) * D1c + y1) * D2c) * 256 + ch0)
                    : (zpad + ch0);
  }
  f4 P = {0.f,0.f,0.f,0.f}, Q = {0.f,0.f,0.f,0.f};
  f4 R = {0.f,0.f,0.f,0.f}, S = {0.f,0.f,0.f,0.f};
  ushort4 bA0[9], bA1[9], bB0[9], bB1[9];
  PLOADR(bA0, -1); PLOADR(bA1, 0);     // pair 0 (rows -1,0)
  PLOADR(bB0, 1);  PLOADR(bB1, 2);     // pair 1 (rows 1,2)
  unsigned short* op = xin + ((size_t)col * D2c) * 256 + ch0;

  // pair 0: no store
  PAIR_BODY(bA0, bA1);
  PAIR_SHIFT();
  PLOADR(bA0, 3); PLOADR(bA1, 4);      // pair 2

  // pairs 1..10: store outputs (2k-2, 2k-1)
#pragma unroll
  for (int k = 1; k <= 10; k++) {
    if (k & 1) { PAIR_BODY(bB0, bB1); } else { PAIR_BODY(bA0, bA1); }
    {
      ushort4 o;
      o.x = f2bf(P.x); o.y = f2bf(P.y); o.z = f2bf(P.z); o.w = f2bf(P.w);
      *(ushort4*)op = o;
      o.x = f2bf(Q.x); o.y = f2bf(Q.y); o.z = f2bf(Q.z); o.w = f2bf(Q.w);
      *(ushort4*)(op + 256) = o;
      op += 512;
    }
    PAIR_SHIFT();
    if (k <= 8) {
      if (k & 1) { PLOADR(bB0, 2 * k + 3); PLOADR(bB1, 2 * k + 4); }
      else       { PLOADR(bA0, 2 * k + 3); PLOADR(bA1, 2 * k + 4); }
    }
  }
}

// ---------------------------------------------------------------- qkv GEMM v6 (unchanged): BM=128, 512 threads, single-barrier pipeline
__global__ __launch_bounds__(512) void k_gemm_qkv(const unsigned short* __restrict__ a_bf,
                                                  const unsigned short* __restrict__ wq2,
                                                  const float* __restrict__ bias,
                                                  unsigned short* __restrict__ out) {
  __shared__ unsigned short As[32768];
  __shared__ unsigned short Bs[8192];
  int m0 = blockIdx.x * 128;
  int tid = threadIdx.x;
  int w = tid >> 6, l = tid & 63;
  int wr = w >> 1, wc = w & 1;
  int lrow = l & 15, lg = l >> 4;

  {
    const char* Ab = (const char*)(a_bf + (size_t)m0 * 256);
    int row = tid >> 2, s = tid & 3;
    int g = s ^ ((row >> 1) & 3);
    const char* src0 = Ab + row * 512 + g * 16;
    char* dst0 = ((char*)As) + w * 1024 + l * 16;
#pragma unroll
    for (int kc = 0; kc < 8; kc++)
      gload16(src0 + kc * 64, dst0 + kc * 8192);
  }
  gload16(((const char*)wq2) + tid * 16, ((char*)Bs) + tid * 16);

  f4 acc[2][4];
  int crow = tid >> 4, cs8 = (tid & 15) * 8;
  for (int nt = 0; nt < 6; nt++) {
    float bvv[4];
#pragma unroll
    for (int j = 0; j < 4; j++) bvv[j] = bias[nt * 128 + wc * 64 + j * 16 + lrow];
#pragma unroll
    for (int i = 0; i < 2; i++)
#pragma unroll
      for (int j = 0; j < 4; j++) acc[i][j] = {0.f, 0.f, 0.f, 0.f};

    for (int kc = 0; kc < 8; kc++) {
      int t = nt * 8 + kc;
      asm volatile("s_barrier" ::: "memory");
      if (t + 1 < 48) {
        gload16(((const char*)wq2) + (size_t)(t + 1) * 8192 + tid * 16,
                ((char*)Bs) + (size_t)((t + 1) & 1) * 8192 + tid * 16);
        asm volatile("s_waitcnt vmcnt(1)" ::: "memory");
      } else {
        asm volatile("s_waitcnt vmcnt(0)" ::: "memory");
      }
      int buf = t & 1;
      bf8 af[2], bf_[4];
#pragma unroll
      for (int i = 0; i < 2; i++) {
        int row = wr * 32 + i * 16 + lrow;
        af[i] = *(const bf8*)&As[kc * 4096 + row * 32 + ((lg ^ ((row >> 1) & 3)) * 8)];
      }
#pragma unroll
      for (int j = 0; j < 4; j++) {
        int rowb = wc * 64 + j * 16 + lrow;
        bf_[j] = *(const bf8*)&Bs[buf * 4096 + rowb * 32 + ((lg ^ ((rowb >> 1) & 3)) * 8)];
      }
#pragma unroll
      for (int i = 0; i < 2; i++)
#pragma unroll
        for (int j = 0; j < 4; j++) acc[i][j] = MFMA16(af[i], bf_[j], acc[i][j]);
    }

    asm volatile("s_barrier" ::: "memory");
    unsigned short* Cs = &Bs[4096];
#pragma unroll
    for (int h = 0; h < 4; h++) {
      if (wr == h) {
#pragma unroll
        for (int i = 0; i < 2; i++)
#pragma unroll
          for (int j = 0; j < 4; j++)
#pragma unroll
            for (int r = 0; r < 4; r++)
              Cs[(i * 16 + lg * 4 + r) * 128 + wc * 64 + j * 16 + lrow] =
                  f2bf(acc[i][j][r] + bvv[j]);
      }
      asm volatile("s_waitcnt lgkmcnt(0)\n\ts_barrier" ::: "memory");
      {
        u8s v0 = *(const u8s*)&Cs[crow * 128 + cs8];
        unsigned short* orow = out + (size_t)(m0 + h * 32 + crow) * 768 + nt * 128 + cs8;
        *(u8s*)orow = v0;
      }
      asm volatile("s_waitcnt lgkmcnt(0)\n\ts_barrier" ::: "memory");
    }
  }
}

// ---------------------------------------------------------------- fine windowed attention (unchanged)
__global__ __launch_bounds__(256) void k_fineattn(const unsigned short* __restrict__ qkv,
                                                  unsigned short* __restrict__ fine) {
  __shared__ unsigned short sm[27136];
  unsigned short* Qs = sm;
  unsigned short* Ks = sm + 9216;
  unsigned short* Vt = sm + 18432;
  unsigned short* Ps = sm;
  int h = blockIdx.x & 3, wid = blockIdx.x >> 2;
  int w2 = wid & 3, w1 = (wid >> 2) & 7, w0 = (wid >> 5) & 7, b = wid >> 8;
  int tid = threadIdx.x;
  int tok = tid >> 1, half = tid & 1;
  if (tok < 125) {
    int i0 = tok / 25, rr = tok % 25, i1 = rr / 5, i2 = rr % 5;
    int n = ((b * D0c + w0 * 5 + i0) * D1c + w1 * 5 + i1) * D2c + w2 * 5 + i2;
    const u8s* qp = (const u8s*)(qkv + (size_t)n * 768 + h * 64 + half * 32);
    const u8s* kp = (const u8s*)(qkv + (size_t)n * 768 + 256 + h * 64 + half * 32);
    const unsigned short* vp = qkv + (size_t)n * 768 + 512 + h * 64 + half * 32;
#pragma unroll
    for (int e = 0; e < 4; e++) {
      *(u8s*)&Qs[tok * 72 + half * 32 + e * 8] = qp[e];
      *(u8s*)&Ks[tok * 72 + half * 32 + e * 8] = kp[e];
    }
#pragma unroll
    for (int d = 0; d < 32; d++) Vt[(half * 32 + d) * 136 + tok] = vp[d];
  } else {
    u8s z = {0, 0, 0, 0, 0, 0, 0, 0};
#pragma unroll
    for (int e = 0; e < 4; e++) {
      *(u8s*)&Qs[tok * 72 + half * 32 + e * 8] = z;
      *(u8s*)&Ks[tok * 72 + half * 32 + e * 8] = z;
    }
#pragma unroll
    for (int d = 0; d < 32; d++) Vt[(half * 32 + d) * 136 + tok] = 0;
  }
  __syncthreads();
  int wv = tid >> 6, ln = tid & 63, lrow = ln & 15, lg = ln >> 4;
  f4 s[2][8];
#pragma unroll
  for (int mi = 0; mi < 2; mi++)
#pragma unroll
    for (int ni = 0; ni < 8; ni++) s[mi][ni] = {0.f, 0.f, 0.f, 0.f};
  bf8 aq[2][2];
#pragma unroll
  for (int ks = 0; ks < 2; ks++)
#pragma unroll
    for (int mi = 0; mi < 2; mi++)
      aq[mi][ks] = *(const bf8*)&Qs[(wv * 32 + mi * 16 + lrow) * 72 + ks * 32 + lg * 8];
#pragma unroll
  for (int ni = 0; ni < 8; ni++) {
#pragma unroll
    for (int ks = 0; ks < 2; ks++) {
      bf8 bk = *(const bf8*)&Ks[(ni * 16 + lrow) * 72 + ks * 32 + lg * 8];
      s[0][ni] = MFMA16(aq[0][ks], bk, s[0][ni]);
      s[1][ni] = MFMA16(aq[1][ks], bk, s[1][ni]);
    }
  }
#pragma unroll
  for (int mi = 0; mi < 2; mi++) {
#pragma unroll
    for (int j = 0; j < 4; j++) {
      float mx = -3e38f;
#pragma unroll
      for (int ni = 0; ni < 8; ni++) {
        int col = ni * 16 + lrow;
        float v = (col < 125) ? s[mi][ni][j] * 0.125f : -3e38f;
        s[mi][ni][j] = v;
        mx = fmaxf(mx, v);
      }
#pragma unroll
      for (int m = 8; m >= 1; m >>= 1) mx = fmaxf(mx, __shfl_xor(mx, m));
      float sum = 0.f;
#pragma unroll
      for (int ni = 0; ni < 8; ni++) {
        float p = __expf(s[mi][ni][j] - mx);
        s[mi][ni][j] = p;
        sum += p;
      }
#pragma unroll
      for (int m = 8; m >= 1; m >>= 1) sum += __shfl_xor(sum, m);
      float inv = 1.f / sum;
#pragma unroll
      for (int ni = 0; ni < 8; ni++) s[mi][ni][j] *= inv;
    }
  }
  __syncthreads();
#pragma unroll
  for (int mi = 0; mi < 2; mi++)
#pragma unroll
    for (int ni = 0; ni < 8; ni++)
#pragma unroll
      for (int j = 0; j < 4; j++)
        Ps[(wv * 32 + mi * 16 + lg * 4 + j) * 136 + ni * 16 + lrow] = f2bf(s[mi][ni][j]);
  __syncthreads();
  f4 o[2][4];
#pragma unroll
  for (int mi = 0; mi < 2; mi++)
#pragma unroll
    for (int ni = 0; ni < 4; ni++) o[mi][ni] = {0.f, 0.f, 0.f, 0.f};
#pragma unroll
  for (int ks = 0; ks < 4; ks++) {
    bf8 ap0 = *(const bf8*)&Ps[(wv * 32 + 0 + lrow) * 136 + ks * 32 + lg * 8];
    bf8 ap1 = *(const bf8*)&Ps[(wv * 32 + 16 + lrow) * 136 + ks * 32 + lg * 8];
#pragma unroll
    for (int ni = 0; ni < 4; ni++) {
      bf8 bv = *(const bf8*)&Vt[(ni * 16 + lrow) * 136 + ks * 32 + lg * 8];
      o[0][ni] = MFMA16(ap0, bv, o[0][ni]);
      o[1][ni] = MFMA16(ap1, bv, o[1][ni]);
    }
  }
#pragma unroll
  for (int mi = 0; mi < 2; mi++) {
    int rt0 = wv * 32 + mi * 16 + lg * 4;
#pragma unroll
    for (int r = 0; r < 4; r++) {
      int tk = rt0 + r;
      if (tk >= 125) continue;
      int i0 = tk / 25, rr = tk % 25, i1 = rr / 5, i2 = rr % 5;
      int n = ((b * D0c + w0 * 5 + i0) * D1c + w1 * 5 + i1) * D2c + w2 * 5 + i2;
#pragma unroll
      for (int ni = 0; ni < 4; ni++)
        fine[(size_t)n * 256 + h * 64 + ni * 16 + lrow] = f2bf(o[mi][ni][r]);
    }
  }
}

// ---------------------------------------------------------------- pool (dims 0,1 by 5) — vectorized u8s loads (unchanged)
__global__ __launch_bounds__(128) void k_pool(const unsigned short* __restrict__ qkv,
                                              unsigned short* __restrict__ qc,
                                              unsigned short* __restrict__ kc,
                                              unsigned short* __restrict__ vct) {
  int ct = blockIdx.x;
  int tid = threadIdx.x;
  if (tid >= 96) return;
  int z2 = ct % 20; int t = ct / 20; int c1 = t & 7; int c0 = (t >> 3) & 7; int b = t >> 6;
  int off = tid * 8;
  f4 s0 = {0.f, 0.f, 0.f, 0.f}, s1 = {0.f, 0.f, 0.f, 0.f};
  for (int i0 = 0; i0 < 5; i0++)
    for (int i1 = 0; i1 < 5; i1++) {
      int n = ((b * D0c + c0 * 5 + i0) * D1c + c1 * 5 + i1) * D2c + z2;
      u8s v = *(const u8s*)(qkv + (size_t)n * 768 + off);
      s0.x += bf2f(v[0]); s0.y += bf2f(v[1]); s0.z += bf2f(v[2]); s0.w += bf2f(v[3]);
      s1.x += bf2f(v[4]); s1.y += bf2f(v[5]); s1.z += bf2f(v[6]); s1.w += bf2f(v[7]);
    }
  const float sc = 1.f / 25.f;
  s0.x *= sc; s0.y *= sc; s0.z *= sc; s0.w *= sc;
  s1.x *= sc; s1.y *= sc; s1.z *= sc; s1.w *= sc;
  if (off < 512) {
    unsigned short* dst = (off < 256) ? (qc + (size_t)ct * 256 + off)
                                      : (kc + (size_t)ct * 256 + (off - 256));
    u8s o;
    o[0] = f2bf(s0.x); o[1] = f2bf(s0.y); o[2] = f2bf(s0.z); o[3] = f2bf(s0.w);
    o[4] = f2bf(s1.x); o[5] = f2bf(s1.y); o[6] = f2bf(s1.z); o[7] = f2bf(s1.w);
    *(u8s*)dst = o;
  } else {
    int vch = off - 512;
    int h = vch >> 6, d0 = vch & 63;
    int tk = ct - b * 1280;
    unsigned short* vb = vct + (((size_t)b * 4 + h) * 64 + d0) * 1288 + tk;
    vb[0 * 1288] = f2bf(s0.x); vb[1 * 1288] = f2bf(s0.y);
    vb[2 * 1288] = f2bf(s0.z); vb[3 * 1288] = f2bf(s0.w);
    vb[4 * 1288] = f2bf(s1.x); vb[5 * 1288] = f2bf(s1.y);
    vb[6 * 1288] = f2bf(s1.z); vb[7 * 1288] = f2bf(s1.w);
  }
}

// ---------------------------------------------------------------- coarse attention (flash, K-tile=64) (unchanged)
__global__ __launch_bounds__(256) void k_coarse(const unsigned short* __restrict__ qc,
                                                const unsigned short* __restrict__ kc,
                                                const unsigned short* __restrict__ vct,
                                                float* __restrict__ oc) {
  __shared__ unsigned short Qs[9216];
  __shared__ unsigned short KP[9216];
  __shared__ unsigned short Vts[4608];
  int qt = blockIdx.x;
  int b = blockIdx.y >> 2, h = blockIdx.y & 3;
  int tid = threadIdx.x, wv = tid >> 6, ln = tid & 63, lrow = ln & 15, lg = ln >> 4;
  {
    int tk = tid >> 1, half = tid & 1;
    const u8s* qp = (const u8s*)(qc + (size_t)(b * 1280 + qt * 128 + tk) * 256 + h * 64 + half * 32);
#pragma unroll
    for (int e = 0; e < 4; e++) *(u8s*)&Qs[tk * 72 + half * 32 + e * 8] = qp[e];
  }
  float mrun[2][4], srun[2][4];
  f4 o[2][4];
#pragma unroll
  for (int mi = 0; mi < 2; mi++)
#pragma unroll
    for (int j = 0; j < 4; j++) { mrun[mi][j] = -3e38f; srun[mi][j] = 0.f; }
#pragma unroll
  for (int mi = 0; mi < 2; mi++)
#pragma unroll
    for (int ni = 0; ni < 4; ni++) o[mi][ni] = {0.f, 0.f, 0.f, 0.f};

  int ktok = tid >> 2, kq = (tid & 3) * 16;
  int vd = tid >> 2, vtc = (tid & 3) * 16;

  for (int kt = 0; kt < 20; kt++) {
    {
      const u8s* kp = (const u8s*)(kc + (size_t)(b * 1280 + kt * 64 + ktok) * 256 + h * 64 + kq);
      *(u8s*)&KP[ktok * 72 + kq] = kp[0];
      *(u8s*)&KP[ktok * 72 + kq + 8] = kp[1];
      const u8s* vp = (const u8s*)(vct + (((size_t)b * 4 + h) * 64 + vd) * 1288 + kt * 64 + vtc);
      *(u8s*)&Vts[vd * 72 + vtc] = vp[0];
      *(u8s*)&Vts[vd * 72 + vtc + 8] = vp[1];
    }
    __syncthreads();
    f4 s[2][4];
#pragma unroll
    for (int mi = 0; mi < 2; mi++)
#pragma unroll
      for (int ni = 0; ni < 4; ni++) s[mi][ni] = {0.f, 0.f, 0.f, 0.f};
    bf8 aq[2][2];
#pragma unroll
    for (int ks = 0; ks < 2; ks++)
#pragma unroll
      for (int mi = 0; mi < 2; mi++)
        aq[mi][ks] = *(const bf8*)&Qs[(wv * 32 + mi * 16 + lrow) * 72 + ks * 32 + lg * 8];
#pragma unroll
    for (int ni = 0; ni < 4; ni++) {
#pragma unroll
      for (int ks = 0; ks < 2; ks++) {
        bf8 bk = *(const bf8*)&KP[(ni * 16 + lrow) * 72 + ks * 32 + lg * 8];
        s[0][ni] = MFMA16(aq[0][ks], bk, s[0][ni]);
        s[1][ni] = MFMA16(aq[1][ks], bk, s[1][ni]);
      }
    }
#pragma unroll
    for (int mi = 0; mi < 2; mi++) {
#pragma unroll
      for (int j = 0; j < 4; j++) {
        float mx = -3e38f;
#pragma unroll
        for (int ni = 0; ni < 4; ni++) {
          float v = s[mi][ni][j] * 0.125f;
          s[mi][ni][j] = v;
          mx = fmaxf(mx, v);
        }
#pragma unroll
        for (int m = 8; m >= 1; m >>= 1) mx = fmaxf(mx, __shfl_xor(mx, m));
        float nm = fmaxf(mrun[mi][j], mx);
        float alpha = __expf(mrun[mi][j] - nm);
        mrun[mi][j] = nm;
        float sum = 0.f;
#pragma unroll
        for (int ni = 0; ni < 4; ni++) {
          float p = __expf(s[mi][ni][j] - nm);
          s[mi][ni][j] = p;
          sum += p;
        }
#pragma unroll
        for (int m = 8; m >= 1; m >>= 1) sum += __shfl_xor(sum, m);
        srun[mi][j] = srun[mi][j] * alpha + sum;
#pragma unroll
        for (int ni = 0; ni < 4; ni++) o[mi][ni][j] *= alpha;
      }
    }
    __syncthreads();
#pragma unroll
    for (int mi = 0; mi < 2; mi++)
#pragma unroll
      for (int ni = 0; ni < 4; ni++)
#pragma unroll
        for (int j = 0; j < 4; j++)
          KP[(wv * 32 + mi * 16 + lg * 4 + j) * 72 + ni * 16 + lrow] = f2bf(s[mi][ni][j]);
    __syncthreads();
#pragma unroll
    for (int ks = 0; ks < 2; ks++) {
      bf8 ap0 = *(const bf8*)&KP[(wv * 32 + 0 + lrow) * 72 + ks * 32 + lg * 8];
      bf8 ap1 = *(const bf8*)&KP[(wv * 32 + 16 + lrow) * 72 + ks * 32 + lg * 8];
#pragma unroll
      for (int ni = 0; ni < 4; ni++) {
        bf8 bv = *(const bf8*)&Vts[(ni * 16 + lrow) * 72 + ks * 32 + lg * 8];
        o[0][ni] = MFMA16(ap0, bv, o[0][ni]);
        o[1][ni] = MFMA16(ap1, bv, o[1][ni]);
      }
    }
    __syncthreads();
  }
#pragma unroll
  for (int mi = 0; mi < 2; mi++)
#pragma unroll
    for (int j = 0; j < 4; j++) {
      float inv = 1.f / srun[mi][j];
      int row = qt * 128 + wv * 32 + mi * 16 + lg * 4 + j;
      float* orow = oc + ((size_t)(b * 1280 + row)) * 256 + h * 64;
#pragma unroll
      for (int ni = 0; ni < 4; ni++) orow[ni * 16 + lrow] = o[mi][ni][j] * inv;
    }
}

// ---------------------------------------------------------------- lowrank on coarse tokens (unchanged)
__global__ __launch_bounds__(256) void k_lowrank(const float* __restrict__ oc,
                                                 const float* __restrict__ lrd,
                                                 const float* __restrict__ lru,
                                                 float* __restrict__ oclr) {
  __shared__ float tmp[16 * 64];
  int t0 = blockIdx.x * 16;
  int tid = threadIdx.x;
  int i = tid >> 4, r4 = (tid & 15) * 4;
  f4 a = {0.f, 0.f, 0.f, 0.f};
  const float* orow = oc + (size_t)(t0 + i) * 256;
  for (int k = 0; k < 256; k++) {
    float ov = orow[k];
    const f4 w = *(const f4*)&lrd[k * 64 + r4];
    a.x += ov * w.x; a.y += ov * w.y; a.z += ov * w.z; a.w += ov * w.w;
  }
  *(f4*)&tmp[i * 64 + r4] = a;
  __syncthreads();
  int c16 = (tid & 15) * 16;
  f4 acc0 = {0.f,0.f,0.f,0.f}, acc1 = {0.f,0.f,0.f,0.f}, acc2 = {0.f,0.f,0.f,0.f}, acc3 = {0.f,0.f,0.f,0.f};
  for (int r = 0; r < 64; r++) {
    float tv = tmp[i * 64 + r];
    const f4* wr = (const f4*)&lru[r * 256 + c16];
    f4 w0 = wr[0], w1 = wr[1], w2 = wr[2], w3 = wr[3];
    acc0.x += tv * w0.x; acc0.y += tv * w0.y; acc0.z += tv * w0.z; acc0.w += tv * w0.w;
    acc1.x += tv * w1.x; acc1.y += tv * w1.y; acc1.z += tv * w1.z; acc1.w += tv * w1.w;
    acc2.x += tv * w2.x; acc2.y += tv * w2.y; acc2.z += tv * w2.z; acc2.w += tv * w2.w;
    acc3.x += tv * w3.x; acc3.y += tv * w3.y; acc3.z += tv * w3.z; acc3.w += tv * w3.w;
  }
  float* outr = oclr + (size_t)(t0 + i) * 256 + c16;
  *(f4*)&outr[0] = acc0; *(f4*)&outr[4] = acc1; *(f4*)&outr[8] = acc2; *(f4*)&outr[12] = acc3;
}

// ---------------------------------------------------------------- proj GEMM v3 (unchanged)
__global__ __launch_bounds__(256) void k_gemm_proj(const unsigned short* __restrict__ fine,
                                                   const float* __restrict__ oclr,
                                                   const unsigned short* __restrict__ wp2,
                                                   const float* __restrict__ bias,
                                                   const unsigned short* __restrict__ xin,
                                                   unsigned short* __restrict__ out1) {
  __shared__ unsigned short As[16384];
  __shared__ unsigned short Bs[8192];
  int m0 = blockIdx.x * 64;
  int tid = threadIdx.x;
  int w = tid >> 6, l = tid & 63;
  int wr = w >> 1, wc = w & 1;
  int lrow = l & 15, lg = l >> 4;

  {
    const char* gB = (const char*)wp2;
    char* lB = (char*)Bs;
    gload16(gB + tid * 16, lB + w * 1024 + l * 16);
    gload16(gB + 4096 + tid * 16, lB + 4096 + w * 1024 + l * 16);
  }
  {
    int row = tid >> 2, s = tid & 3;
    int g = s ^ ((row >> 1) & 3);
    int nrow = m0 + row;
    int z2 = nrow % D2c; int tt = nrow / D2c; int z1 = tt % D1c; tt /= D1c;
    int z0 = tt % D0c; int bb = tt / D0c;
    int ct = ((bb * 8 + z0 / 5) * 8 + z1 / 5) * 20 + z2;
    const unsigned short* fp = fine + (size_t)nrow * 256 + g * 8;
    const float* cp = oclr + (size_t)ct * 256 + g * 8;
#pragma unroll
    for (int kc = 0; kc < 8; kc++) {
      u8s fv = *(const u8s*)(fp + kc * 32);
      f4 cv0 = *(const f4*)(cp + kc * 32);
      f4 cv1 = *(const f4*)(cp + kc * 32 + 4);
      u8s t0;
      t0[0] = f2bf(bf2f(fv[0]) + cv0.x); t0[1] = f2bf(bf2f(fv[1]) + cv0.y);
      t0[2] = f2bf(bf2f(fv[2]) + cv0.z); t0[3] = f2bf(bf2f(fv[3]) + cv0.w);
      t0[4] = f2bf(bf2f(fv[4]) + cv1.x); t0[5] = f2bf(bf2f(fv[5]) + cv1.y);
      t0[6] = f2bf(bf2f(fv[6]) + cv1.z); t0[7] = f2bf(bf2f(fv[7]) + cv1.w);
      *(u8s*)&As[kc * 2048 + row * 32 + s * 8] = t0;
    }
  }
  asm volatile("s_waitcnt lgkmcnt(0)\n\ts_barrier" ::: "memory");

  int buf = 0;
  f4 acc[2][4];
  for (int nt = 0; nt < 2; nt++) {
    float bvv[4];
#pragma unroll
    for (int j = 0; j < 4; j++) bvv[j] = bias[nt * 128 + wc * 64 + j * 16 + lrow];
#pragma unroll
    for (int i = 0; i < 2; i++)
#pragma unroll
      for (int j = 0; j < 4; j++) acc[i][j] = {0.f, 0.f, 0.f, 0.f};

    for (int kc = 0; kc < 8; kc++) {
      int t = nt * 8 + kc;
      if (t + 1 < 16) {
        const char* gB = (const char*)wp2 + (size_t)(t + 1) * 8192;
        char* lB = ((char*)Bs) + (buf ^ 1) * 8192;
        gload16(gB + tid * 16, lB + w * 1024 + l * 16);
        gload16(gB + 4096 + tid * 16, lB + 4096 + w * 1024 + l * 16);
        asm volatile("s_waitcnt vmcnt(2)\n\ts_barrier" ::: "memory");
      } else {
        asm volatile("s_waitcnt vmcnt(0)\n\ts_barrier" ::: "memory");
      }
      bf8 af[2], bf_[4];
#pragma unroll
      for (int i = 0; i < 2; i++) {
        int row = wr * 32 + i * 16 + lrow;
        af[i] = *(const bf8*)&As[kc * 2048 + row * 32 + ((lg ^ ((row >> 1) & 3)) * 8)];
      }
#pragma unroll
      for (int j = 0; j < 4; j++) {
        int rowb = wc * 64 + j * 16 + lrow;
        bf_[j] = *(const bf8*)&Bs[buf * 4096 + rowb * 32 + ((lg ^ ((rowb >> 1) & 3)) * 8)];
      }
#pragma unroll
      for (int i = 0; i < 2; i++)
#pragma unroll
        for (int j = 0; j < 4; j++) acc[i][j] = MFMA16(af[i], bf_[j], acc[i][j]);
      asm volatile("s_barrier" ::: "memory");
      buf ^= 1;
    }

    unsigned short* Cs = &Bs[(buf ^ 1) * 4096];
    int crow = tid >> 3, cseg = tid & 7;
#pragma unroll
    for (int h = 0; h < 2; h++) {
      if (wr == h) {
#pragma unroll
        for (int i = 0; i < 2; i++)
#pragma unroll
          for (int j = 0; j < 4; j++)
#pragma unroll
            for (int r = 0; r < 4; r++)
              Cs[(i * 16 + lg * 4 + r) * 128 + wc * 64 + j * 16 + lrow] =
                  f2bf(acc[i][j][r] + bvv[j]);
      }
      asm volatile("s_waitcnt lgkmcnt(0)\n\ts_barrier" ::: "memory");
      {
        u8s v0 = *(const u8s*)&Cs[crow * 128 + cseg * 16];
        u8s v1 = *(const u8s*)&Cs[crow * 128 + cseg * 16 + 8];
        const unsigned short* xrow = xin + (size_t)(m0 + h * 32 + crow) * 256 + nt * 128 + cseg * 16;
        u8s x0 = *(const u8s*)xrow;
        u8s x1 = *(const u8s*)(xrow + 8);
        u8s o0, o1;
#pragma unroll
        for (int e = 0; e < 8; e++) {
          o0[e] = f2bf(bf2f(v0[e]) + bf2f(x0[e]));
          o1[e] = f2bf(bf2f(v1[e]) + bf2f(x1[e]));
        }
        unsigned short* orow = out1 + (size_t)(m0 + h * 32 + crow) * 256 + nt * 128 + cseg * 16;
        *(u8s*)orow = o0;
        *(u8s*)(orow + 8) = o1;
      }
      asm volatile("s_waitcnt lgkmcnt(0)\n\ts_barrier" ::: "memory");
    }
  }
}

// ---------------------------------------------------------------- post conv: fused row-pair + rmsnorm + residual
__global__ __launch_bounds__(256) void k_convpost(const unsigned short* __restrict__ o1,
                                                  const float* __restrict__ dw,
                                                  const unsigned short* __restrict__ zpad,
                                                  const float* __restrict__ x,
                                                  const float* __restrict__ anw,
                                                  float* __restrict__ outp) {
  __shared__ float wl[6912];
  for (int i = threadIdx.x; i < 6912; i += 256) wl[i] = dw[i];
  __syncthreads();
  int wv = threadIdx.x >> 6, ln = threadIdx.x & 63;
  int col = blockIdx.x * 4 + wv;
  int z1 = col % D1c; int t = col / D1c; int z0 = t % D0c; int b = t / D0c;
  int ch0 = ln * 4;

  const unsigned short* base[9];
#pragma unroll
  for (int c = 0; c < 9; c++) {
    int dy = c / 3 - 1, dx = c % 3 - 1;
    int y0 = z0 + dy, y1 = z1 + dx;
    bool valid = ((unsigned)y0 < (unsigned)D0c) && ((unsigned)y1 < (unsigned)D1c);
    base[c] = valid ? (o1 + ((size_t)((b * D0c + y0) * D1c + y1) * D2c) * 256 + ch0)
                    : (zpad + ch0);
  }
  f4 P = {0.f,0.f,0.f,0.f}, Q = {0.f,0.f,0.f,0.f};
  f4 R = {0.f,0.f,0.f,0.f}, S = {0.f,0.f,0.f,0.f};
  ushort4 bA0[9], bA1[9], bB0[9], bB1[9];
  PLOADR(bA0, -1); PLOADR(bA1, 0);
  PLOADR(bB0, 1);  PLOADR(bB1, 2);
  const f4 wv4 = *(const f4*)(anw + ch0);
  const float* xp = x + ((size_t)col * D2c) * 256 + ch0;
  float* op = outp + ((size_t)col * D2c) * 256 + ch0;

#define POST_STORE_ACC(ACC)                                                   \
  do {                                                                        \
    float ss = ACC.x * ACC.x + ACC.y * ACC.y + ACC.z * ACC.z + ACC.w * ACC.w; \
    _Pragma("unroll") for (int m = 32; m >= 1; m >>= 1)                       \
        ss += __shfl_xor(ss, m);                                              \
    float rs = rsqrtf(ss * (1.f / 256.f) + 1e-6f);                            \
    f4 xv = *(const f4*)xp;                                                   \
    f4 res;                                                                   \
    res.x = xv.x + ACC.x * wv4.x * rs;                                        \
    res.y = xv.y + ACC.y * wv4.y * rs;                                        \
    res.z = xv.z + ACC.z * wv4.z * rs;                                        \
    res.w = xv.w + ACC.w * wv4.w * rs;                                        \
    *(f4*)op = res;                                                           \
    xp += 256; op += 256;                                                     \
  } while (0)

  // pair 0 (rows -1,0): no store
  PAIR_BODY(bA0, bA1);
  PAIR_SHIFT();
  PLOADR(bA0, 3); PLOADR(bA1, 4);

#pragma unroll
  for (int k = 1; k <= 10; k++) {
    if (k & 1) { PAIR_BODY(bB0, bB1); } else { PAIR_BODY(bA0, bA1); }
    POST_STORE_ACC(P);
    POST_STORE_ACC(Q);
    PAIR_SHIFT();
    if (k <= 8) {
      if (k & 1) { PLOADR(bB0, 2 * k + 3); PLOADR(bB1, 2 * k + 4); }
      else       { PLOADR(bA0, 2 * k + 3); PLOADR(bA1, 2 * k + 4); }
    }
  }
#undef POST_STORE_ACC
}

// ---------------------------------------------------------------- launch
extern "C" void kernel_launch(void* const* d_in, const int* in_sizes, int n_in,
                              void* d_out, int out_size, void* d_ws, size_t ws_size,
                              hipStream_t stream) {
  const float* x          = (const float*)d_in[0];
  const float* norm1_w    = (const float*)d_in[1];
  const float* attn_norm_w= (const float*)d_in[2];
  const float* qkv_w      = (const float*)d_in[3];
  const float* qkv_b      = (const float*)d_in[4];
  const float* proj_w     = (const float*)d_in[5];
  const float* proj_b     = (const float*)d_in[6];
  const float* dw_pre     = (const float*)d_in[7];
  const float* dw_post    = (const float*)d_in[8];
  const float* lr_down    = (const float*)d_in[9];
  const float* lr_up      = (const float*)d_in[10];
  float* outp = (float*)d_out;

  unsigned char* w = (unsigned char*)d_ws;
  size_t off = 0;
  unsigned short* xn   = (unsigned short*)(w + off); off += 65536000ULL;   // reused as `fine`
  unsigned short* xin  = (unsigned short*)(w + off); off += 65536000ULL;
  unsigned short* qkv  = (unsigned short*)(w + off); off += 196608000ULL;
  unsigned short* out1 = (unsigned short*)(w + off); off += 65536000ULL;
  unsigned short* qc   = (unsigned short*)(w + off); off += 2621440ULL;
  unsigned short* kc   = (unsigned short*)(w + off); off += 2621440ULL;
  unsigned short* vct  = (unsigned short*)(w + off); off += 2637824ULL;
  float* oc            = (float*)(w + off);          off += 5242880ULL;
  float* oclr          = (float*)(w + off);          off += 5242880ULL;
  unsigned short* wq   = (unsigned short*)(w + off); off += 393216ULL;
  unsigned short* wp   = (unsigned short*)(w + off); off += 131072ULL;
  unsigned short* zpad = (unsigned short*)(w + off); off += 12288ULL;
  unsigned short* fine = xn;  // xn dead after k_convpre

  k_prepw<<<1025, 256, 0, stream>>>(qkv_w, proj_w, wq, wp, zpad);
  k_rms1<<<32000, 256, 0, stream>>>(x, norm1_w, xn);
  k_convpre<<<1600, 256, 0, stream>>>(xn, dw_pre, zpad, xin);
  k_gemm_qkv<<<1000, 512, 0, stream>>>(xin, wq, qkv_b, qkv);
  k_fineattn<<<4096, 256, 0, stream>>>(qkv, fine);
  k_pool<<<5120, 128, 0, stream>>>(qkv, qc, kc, vct);
  k_coarse<<<dim3(10, 16), 256, 0, stream>>>(qc, kc, vct, oc);
  k_lowrank<<<320, 256, 0, stream>>>(oc, lr_down, lr_up, oclr);
  k_gemm_proj<<<2000, 256, 0, stream>>>(fine, oclr, wp, proj_b, xin, out1);
  k_convpost<<<1600, 256, 0, stream>>>(out1, dw_post, zpad, x, attn_norm_w, outp);
}

// Round 16
// 596.239 us; speedup vs baseline: 1.0224x; 1.0224x over previous
//
#include <hip/hip_runtime.h>

#define D0c 40
#define D1c 40
#define D2c 20
#define NVOX 128000

typedef __attribute__((ext_vector_type(4))) float f4;
typedef __attribute__((ext_vector_type(8))) __bf16 bf8;
typedef __attribute__((ext_vector_type(8))) unsigned short u8s;

static __device__ __forceinline__ unsigned short f2bf(float f) {
  union { float f; unsigned int u; } v; v.f = f;
  unsigned int r = v.u + 0x7fffu + ((v.u >> 16) & 1u);
  return (unsigned short)(r >> 16);
}
static __device__ __forceinline__ float bf2f(unsigned short h) {
  union { unsigned int u; float f; } v; v.u = ((unsigned int)h) << 16;
  return v.f;
}

#define MFMA16(a, b, c) __builtin_amdgcn_mfma_f32_16x16x32_bf16((a), (b), (c), 0, 0, 0)

static __device__ __forceinline__ void gload16(const void* g, void* l) {
  __builtin_amdgcn_global_load_lds((const __attribute__((address_space(1))) unsigned int*)g,
                                   (__attribute__((address_space(3))) unsigned int*)l, 16, 0, 0);
}

// conv inner-step helpers
#define CONV_LOAD(NB, R)                                                      \
  do {                                                                        \
    _Pragma("unroll") for (int c = 0; c < 9; c++)                             \
        NB[c] = *(const ushort4*)(base[c] + (size_t)(R) * 256);               \
  } while (0)

#define CONV_CONSUME(NB)                                                      \
  do {                                                                        \
    f4 cf[9];                                                                 \
    _Pragma("unroll") for (int c = 0; c < 9; c++) {                           \
      cf[c].x = bf2f(NB[c].x); cf[c].y = bf2f(NB[c].y);                       \
      cf[c].z = bf2f(NB[c].z); cf[c].w = bf2f(NB[c].w);                       \
    }                                                                         \
    _Pragma("unroll") for (int c = 0; c < 9; c++) {                           \
      const f4 w0 = *(const f4*)&wl[(c * 3 + 0) * 256 + c0];                  \
      const f4 w1 = *(const f4*)&wl[(c * 3 + 1) * 256 + c0];                  \
      const f4 w2 = *(const f4*)&wl[(c * 3 + 2) * 256 + c0];                  \
      a0 += w2 * cf[c]; a1 += w1 * cf[c]; a2 += w0 * cf[c];                   \
    }                                                                         \
    a1 += cf[4];                                                              \
  } while (0)

#define CONV_SHIFT()                                                          \
  do { a0 = a1; a1 = a2; a2 = (f4){0.f, 0.f, 0.f, 0.f}; } while (0)

// ---------------------------------------------------------------- weight prep (+ zero page)
__global__ __launch_bounds__(256) void k_prepw(const float* __restrict__ qkv_w,
                                               const float* __restrict__ proj_w,
                                               unsigned short* __restrict__ wq,
                                               unsigned short* __restrict__ wp,
                                               unsigned short* __restrict__ zpad) {
  if (blockIdx.x == 1024) {
    u8s z = {0, 0, 0, 0, 0, 0, 0, 0};
    for (int i = threadIdx.x; i < 768; i += 256) *(u8s*)(zpad + i * 8) = z;
    return;
  }
  int id = blockIdx.x * 256 + threadIdx.x;
  if (id < 768 * 256) {
    int kk = id & 31, row = (id >> 5) & 127, kc = (id >> 12) & 7, nt = id >> 15;
    int s = kk >> 3, kj = kk & 7;
    int g = s ^ ((row >> 1) & 3);
    int k = kc * 32 + g * 8 + kj;
    int n = nt * 128 + row;
    wq[id] = f2bf(qkv_w[k * 768 + n]);
  } else {
    int j = id - 768 * 256;
    int kk = j & 31, row = (j >> 5) & 127, kc = (j >> 12) & 7, nt = j >> 15;
    int s = kk >> 3, kj = kk & 7;
    int g = s ^ ((row >> 1) & 3);
    int k = kc * 32 + g * 8 + kj;
    int n = nt * 128 + row;
    wp[j] = f2bf(proj_w[k * 256 + n]);
  }
}

// ---------------------------------------------------------------- rmsnorm (pre)
__global__ __launch_bounds__(256) void k_rms1(const float* __restrict__ x,
                                              const float* __restrict__ w,
                                              unsigned short* __restrict__ xn) {
  int wv = threadIdx.x >> 6, ln = threadIdx.x & 63;
  int n = blockIdx.x * 4 + wv;
  f4 v = ((const f4*)(x + (size_t)n * 256))[ln];
  float ss = v.x * v.x + v.y * v.y + v.z * v.z + v.w * v.w;
#pragma unroll
  for (int m = 32; m >= 1; m >>= 1) ss += __shfl_xor(ss, m);
  float rs = rsqrtf(ss * (1.f / 256.f) + 1e-6f);
  f4 wv4 = ((const f4*)w)[ln];
  ushort4 o;
  o.x = f2bf(v.x * wv4.x * rs); o.y = f2bf(v.y * wv4.y * rs);
  o.z = f2bf(v.z * wv4.z * rs); o.w = f2bf(v.w * wv4.w * rs);
  ((ushort4*)(xn + (size_t)n * 256))[ln] = o;
}

// ---------------------------------------------------------------- dwconv pre: wave=column, 4ch/lane, zero-page, 2-deep prefetch
__global__ __launch_bounds__(256) void k_convpre(const unsigned short* __restrict__ xn,
                                                 const float* __restrict__ dw,
                                                 const unsigned short* __restrict__ zpad,
                                                 unsigned short* __restrict__ xin) {
  __shared__ float wl[6912];
  for (int i = threadIdx.x; i < 6912; i += 256) wl[i] = dw[i];
  __syncthreads();
  int wv = threadIdx.x >> 6, ln = threadIdx.x & 63;
  int col = blockIdx.x * 4 + wv;
  int z1 = col % D1c; int t = col / D1c; int z0 = t % D0c; int b = t / D0c;
  int c0 = ln * 4;

  const unsigned short* base[9];
#pragma unroll
  for (int c = 0; c < 9; c++) {
    int dy = c / 3 - 1, dx = c % 3 - 1;
    int y0 = z0 + dy, y1 = z1 + dx;
    bool valid = ((unsigned)y0 < (unsigned)D0c) && ((unsigned)y1 < (unsigned)D1c);
    base[c] = valid ? (xn + ((size_t)((b * D0c + y0) * D1c + y1) * D2c) * 256 + c0)
                    : (zpad + c0);
  }
  f4 a0 = {0.f,0.f,0.f,0.f}, a1 = {0.f,0.f,0.f,0.f}, a2 = {0.f,0.f,0.f,0.f};
  ushort4 n0[9], n1[9];
  CONV_LOAD(n0, 0);
  CONV_LOAD(n1, 1);
  unsigned short* op = xin + ((size_t)col * D2c) * 256 + c0;

  CONV_CONSUME(n0);
  CONV_SHIFT();
  CONV_LOAD(n0, 2);
  CONV_CONSUME(n1);
  {
    ushort4 o;
    o.x = f2bf(a0.x); o.y = f2bf(a0.y); o.z = f2bf(a0.z); o.w = f2bf(a0.w);
    *(ushort4*)op = o; op += 256;
  }
  CONV_SHIFT();
  CONV_LOAD(n1, 3);

  for (int z = 2; z < 20; z += 2) {
    CONV_CONSUME(n0);
    {
      ushort4 o;
      o.x = f2bf(a0.x); o.y = f2bf(a0.y); o.z = f2bf(a0.z); o.w = f2bf(a0.w);
      *(ushort4*)op = o; op += 256;
    }
    CONV_SHIFT();
    int r2 = (z + 2 > 19) ? 19 : (z + 2);
    CONV_LOAD(n0, r2);

    CONV_CONSUME(n1);
    {
      ushort4 o;
      o.x = f2bf(a0.x); o.y = f2bf(a0.y); o.z = f2bf(a0.z); o.w = f2bf(a0.w);
      *(ushort4*)op = o; op += 256;
    }
    CONV_SHIFT();
    int r3 = (z + 3 > 19) ? 19 : (z + 3);
    CONV_LOAD(n1, r3);
  }
  {
    ushort4 o;
    o.x = f2bf(a0.x); o.y = f2bf(a0.y); o.z = f2bf(a0.z); o.w = f2bf(a0.w);
    *(ushort4*)op = o;
  }
}

// ---------------------------------------------------------------- qkv GEMM v6: BM=128, 512 threads, single-barrier pipeline.
__global__ __launch_bounds__(512) void k_gemm_qkv(const unsigned short* __restrict__ a_bf,
                                                  const unsigned short* __restrict__ wq2,
                                                  const float* __restrict__ bias,
                                                  unsigned short* __restrict__ out) {
  __shared__ unsigned short As[32768];
  __shared__ unsigned short Bs[8192];
  int m0 = blockIdx.x * 128;
  int tid = threadIdx.x;
  int w = tid >> 6, l = tid & 63;
  int wr = w >> 1, wc = w & 1;
  int lrow = l & 15, lg = l >> 4;

  {
    const char* Ab = (const char*)(a_bf + (size_t)m0 * 256);
    int row = tid >> 2, s = tid & 3;
    int g = s ^ ((row >> 1) & 3);
    const char* src0 = Ab + row * 512 + g * 16;
    char* dst0 = ((char*)As) + w * 1024 + l * 16;
#pragma unroll
    for (int kc = 0; kc < 8; kc++)
      gload16(src0 + kc * 64, dst0 + kc * 8192);
  }
  gload16(((const char*)wq2) + tid * 16, ((char*)Bs) + tid * 16);

  f4 acc[2][4];
  int crow = tid >> 4, cs8 = (tid & 15) * 8;
  for (int nt = 0; nt < 6; nt++) {
    float bvv[4];
#pragma unroll
    for (int j = 0; j < 4; j++) bvv[j] = bias[nt * 128 + wc * 64 + j * 16 + lrow];
#pragma unroll
    for (int i = 0; i < 2; i++)
#pragma unroll
      for (int j = 0; j < 4; j++) acc[i][j] = {0.f, 0.f, 0.f, 0.f};

    for (int kc = 0; kc < 8; kc++) {
      int t = nt * 8 + kc;
      asm volatile("s_barrier" ::: "memory");
      if (t + 1 < 48) {
        gload16(((const char*)wq2) + (size_t)(t + 1) * 8192 + tid * 16,
                ((char*)Bs) + (size_t)((t + 1) & 1) * 8192 + tid * 16);
        asm volatile("s_waitcnt vmcnt(1)" ::: "memory");
      } else {
        asm volatile("s_waitcnt vmcnt(0)" ::: "memory");
      }
      int buf = t & 1;
      bf8 af[2], bf_[4];
#pragma unroll
      for (int i = 0; i < 2; i++) {
        int row = wr * 32 + i * 16 + lrow;
        af[i] = *(const bf8*)&As[kc * 4096 + row * 32 + ((lg ^ ((row >> 1) & 3)) * 8)];
      }
#pragma unroll
      for (int j = 0; j < 4; j++) {
        int rowb = wc * 64 + j * 16 + lrow;
        bf_[j] = *(const bf8*)&Bs[buf * 4096 + rowb * 32 + ((lg ^ ((rowb >> 1) & 3)) * 8)];
      }
#pragma unroll
      for (int i = 0; i < 2; i++)
#pragma unroll
        for (int j = 0; j < 4; j++) acc[i][j] = MFMA16(af[i], bf_[j], acc[i][j]);
    }

    asm volatile("s_barrier" ::: "memory");
    unsigned short* Cs = &Bs[4096];
#pragma unroll
    for (int h = 0; h < 4; h++) {
      if (wr == h) {
#pragma unroll
        for (int i = 0; i < 2; i++)
#pragma unroll
          for (int j = 0; j < 4; j++)
#pragma unroll
            for (int r = 0; r < 4; r++)
              Cs[(i * 16 + lg * 4 + r) * 128 + wc * 64 + j * 16 + lrow] =
                  f2bf(acc[i][j][r] + bvv[j]);
      }
      asm volatile("s_waitcnt lgkmcnt(0)\n\ts_barrier" ::: "memory");
      {
        u8s v0 = *(const u8s*)&Cs[crow * 128 + cs8];
        unsigned short* orow = out + (size_t)(m0 + h * 32 + crow) * 768 + nt * 128 + cs8;
        *(u8s*)orow = v0;
      }
      asm volatile("s_waitcnt lgkmcnt(0)\n\ts_barrier" ::: "memory");
    }
  }
}

// ---------------------------------------------------------------- fine windowed attention
__global__ __launch_bounds__(256) void k_fineattn(const unsigned short* __restrict__ qkv,
                                                  unsigned short* __restrict__ fine) {
  __shared__ unsigned short sm[27136];
  unsigned short* Qs = sm;
  unsigned short* Ks = sm + 9216;
  unsigned short* Vt = sm + 18432;
  unsigned short* Ps = sm;
  int h = blockIdx.x & 3, wid = blockIdx.x >> 2;
  int w2 = wid & 3, w1 = (wid >> 2) & 7, w0 = (wid >> 5) & 7, b = wid >> 8;
  int tid = threadIdx.x;
  int tok = tid >> 1, half = tid & 1;
  if (tok < 125) {
    int i0 = tok / 25, rr = tok % 25, i1 = rr / 5, i2 = rr % 5;
    int n = ((b * D0c + w0 * 5 + i0) * D1c + w1 * 5 + i1) * D2c + w2 * 5 + i2;
    const u8s* qp = (const u8s*)(qkv + (size_t)n * 768 + h * 64 + half * 32);
    const u8s* kp = (const u8s*)(qkv + (size_t)n * 768 + 256 + h * 64 + half * 32);
    const unsigned short* vp = qkv + (size_t)n * 768 + 512 + h * 64 + half * 32;
#pragma unroll
    for (int e = 0; e < 4; e++) {
      *(u8s*)&Qs[tok * 72 + half * 32 + e * 8] = qp[e];
      *(u8s*)&Ks[tok * 72 + half * 32 + e * 8] = kp[e];
    }
#pragma unroll
    for (int d = 0; d < 32; d++) Vt[(half * 32 + d) * 136 + tok] = vp[d];
  } else {
    u8s z = {0, 0, 0, 0, 0, 0, 0, 0};
#pragma unroll
    for (int e = 0; e < 4; e++) {
      *(u8s*)&Qs[tok * 72 + half * 32 + e * 8] = z;
      *(u8s*)&Ks[tok * 72 + half * 32 + e * 8] = z;
    }
#pragma unroll
    for (int d = 0; d < 32; d++) Vt[(half * 32 + d) * 136 + tok] = 0;
  }
  __syncthreads();
  int wv = tid >> 6, ln = tid & 63, lrow = ln & 15, lg = ln >> 4;
  f4 s[2][8];
#pragma unroll
  for (int mi = 0; mi < 2; mi++)
#pragma unroll
    for (int ni = 0; ni < 8; ni++) s[mi][ni] = {0.f, 0.f, 0.f, 0.f};
  bf8 aq[2][2];
#pragma unroll
  for (int ks = 0; ks < 2; ks++)
#pragma unroll
    for (int mi = 0; mi < 2; mi++)
      aq[mi][ks] = *(const bf8*)&Qs[(wv * 32 + mi * 16 + lrow) * 72 + ks * 32 + lg * 8];
#pragma unroll
  for (int ni = 0; ni < 8; ni++) {
#pragma unroll
    for (int ks = 0; ks < 2; ks++) {
      bf8 bk = *(const bf8*)&Ks[(ni * 16 + lrow) * 72 + ks * 32 + lg * 8];
      s[0][ni] = MFMA16(aq[0][ks], bk, s[0][ni]);
      s[1][ni] = MFMA16(aq[1][ks], bk, s[1][ni]);
    }
  }
#pragma unroll
  for (int mi = 0; mi < 2; mi++) {
#pragma unroll
    for (int j = 0; j < 4; j++) {
      float mx = -3e38f;
#pragma unroll
      for (int ni = 0; ni < 8; ni++) {
        int col = ni * 16 + lrow;
        float v = (col < 125) ? s[mi][ni][j] * 0.125f : -3e38f;
        s[mi][ni][j] = v;
        mx = fmaxf(mx, v);
      }
#pragma unroll
      for (int m = 8; m >= 1; m >>= 1) mx = fmaxf(mx, __shfl_xor(mx, m));
      float sum = 0.f;
#pragma unroll
      for (int ni = 0; ni < 8; ni++) {
        float p = __expf(s[mi][ni][j] - mx);
        s[mi][ni][j] = p;
        sum += p;
      }
#pragma unroll
      for (int m = 8; m >= 1; m >>= 1) sum += __shfl_xor(sum, m);
      float inv = 1.f / sum;
#pragma unroll
      for (int ni = 0; ni < 8; ni++) s[mi][ni][j] *= inv;
    }
  }
  __syncthreads();
#pragma unroll
  for (int mi = 0; mi < 2; mi++)
#pragma unroll
    for (int ni = 0; ni < 8; ni++)
#pragma unroll
      for (int j = 0; j < 4; j++)
        Ps[(wv * 32 + mi * 16 + lg * 4 + j) * 136 + ni * 16 + lrow] = f2bf(s[mi][ni][j]);
  __syncthreads();
  f4 o[2][4];
#pragma unroll
  for (int mi = 0; mi < 2; mi++)
#pragma unroll
    for (int ni = 0; ni < 4; ni++) o[mi][ni] = {0.f, 0.f, 0.f, 0.f};
#pragma unroll
  for (int ks = 0; ks < 4; ks++) {
    bf8 ap0 = *(const bf8*)&Ps[(wv * 32 + 0 + lrow) * 136 + ks * 32 + lg * 8];
    bf8 ap1 = *(const bf8*)&Ps[(wv * 32 + 16 + lrow) * 136 + ks * 32 + lg * 8];
#pragma unroll
    for (int ni = 0; ni < 4; ni++) {
      bf8 bv = *(const bf8*)&Vt[(ni * 16 + lrow) * 136 + ks * 32 + lg * 8];
      o[0][ni] = MFMA16(ap0, bv, o[0][ni]);
      o[1][ni] = MFMA16(ap1, bv, o[1][ni]);
    }
  }
#pragma unroll
  for (int mi = 0; mi < 2; mi++) {
    int rt0 = wv * 32 + mi * 16 + lg * 4;
#pragma unroll
    for (int r = 0; r < 4; r++) {
      int tk = rt0 + r;
      if (tk >= 125) continue;
      int i0 = tk / 25, rr = tk % 25, i1 = rr / 5, i2 = rr % 5;
      int n = ((b * D0c + w0 * 5 + i0) * D1c + w1 * 5 + i1) * D2c + w2 * 5 + i2;
#pragma unroll
      for (int ni = 0; ni < 4; ni++)
        fine[(size_t)n * 256 + h * 64 + ni * 16 + lrow] = f2bf(o[mi][ni][r]);
    }
  }
}

// ---------------------------------------------------------------- pool (dims 0,1 by 5) — vectorized u8s loads
__global__ __launch_bounds__(128) void k_pool(const unsigned short* __restrict__ qkv,
                                              unsigned short* __restrict__ qc,
                                              unsigned short* __restrict__ kc,
                                              unsigned short* __restrict__ vct) {
  int ct = blockIdx.x;
  int tid = threadIdx.x;
  if (tid >= 96) return;
  int z2 = ct % 20; int t = ct / 20; int c1 = t & 7; int c0 = (t >> 3) & 7; int b = t >> 6;
  int off = tid * 8;
  f4 s0 = {0.f, 0.f, 0.f, 0.f}, s1 = {0.f, 0.f, 0.f, 0.f};
  for (int i0 = 0; i0 < 5; i0++)
    for (int i1 = 0; i1 < 5; i1++) {
      int n = ((b * D0c + c0 * 5 + i0) * D1c + c1 * 5 + i1) * D2c + z2;
      u8s v = *(const u8s*)(qkv + (size_t)n * 768 + off);
      s0.x += bf2f(v[0]); s0.y += bf2f(v[1]); s0.z += bf2f(v[2]); s0.w += bf2f(v[3]);
      s1.x += bf2f(v[4]); s1.y += bf2f(v[5]); s1.z += bf2f(v[6]); s1.w += bf2f(v[7]);
    }
  const float sc = 1.f / 25.f;
  s0.x *= sc; s0.y *= sc; s0.z *= sc; s0.w *= sc;
  s1.x *= sc; s1.y *= sc; s1.z *= sc; s1.w *= sc;
  if (off < 512) {
    unsigned short* dst = (off < 256) ? (qc + (size_t)ct * 256 + off)
                                      : (kc + (size_t)ct * 256 + (off - 256));
    u8s o;
    o[0] = f2bf(s0.x); o[1] = f2bf(s0.y); o[2] = f2bf(s0.z); o[3] = f2bf(s0.w);
    o[4] = f2bf(s1.x); o[5] = f2bf(s1.y); o[6] = f2bf(s1.z); o[7] = f2bf(s1.w);
    *(u8s*)dst = o;
  } else {
    int vch = off - 512;
    int h = vch >> 6, d0 = vch & 63;
    int tk = ct - b * 1280;
    unsigned short* vb = vct + (((size_t)b * 4 + h) * 64 + d0) * 1288 + tk;
    vb[0 * 1288] = f2bf(s0.x); vb[1 * 1288] = f2bf(s0.y);
    vb[2 * 1288] = f2bf(s0.z); vb[3 * 1288] = f2bf(s0.w);
    vb[4 * 1288] = f2bf(s1.x); vb[5 * 1288] = f2bf(s1.y);
    vb[6 * 1288] = f2bf(s1.z); vb[7 * 1288] = f2bf(s1.w);
  }
}

// ---------------------------------------------------------------- coarse attention (flash, K-tile=64)
__global__ __launch_bounds__(256) void k_coarse(const unsigned short* __restrict__ qc,
                                                const unsigned short* __restrict__ kc,
                                                const unsigned short* __restrict__ vct,
                                                float* __restrict__ oc) {
  __shared__ unsigned short Qs[9216];
  __shared__ unsigned short KP[9216];
  __shared__ unsigned short Vts[4608];
  int qt = blockIdx.x;
  int b = blockIdx.y >> 2, h = blockIdx.y & 3;
  int tid = threadIdx.x, wv = tid >> 6, ln = tid & 63, lrow = ln & 15, lg = ln >> 4;
  {
    int tk = tid >> 1, half = tid & 1;
    const u8s* qp = (const u8s*)(qc + (size_t)(b * 1280 + qt * 128 + tk) * 256 + h * 64 + half * 32);
#pragma unroll
    for (int e = 0; e < 4; e++) *(u8s*)&Qs[tk * 72 + half * 32 + e * 8] = qp[e];
  }
  float mrun[2][4], srun[2][4];
  f4 o[2][4];
#pragma unroll
  for (int mi = 0; mi < 2; mi++)
#pragma unroll
    for (int j = 0; j < 4; j++) { mrun[mi][j] = -3e38f; srun[mi][j] = 0.f; }
#pragma unroll
  for (int mi = 0; mi < 2; mi++)
#pragma unroll
    for (int ni = 0; ni < 4; ni++) o[mi][ni] = {0.f, 0.f, 0.f, 0.f};

  int ktok = tid >> 2, kq = (tid & 3) * 16;
  int vd = tid >> 2, vtc = (tid & 3) * 16;

  for (int kt = 0; kt < 20; kt++) {
    {
      const u8s* kp = (const u8s*)(kc + (size_t)(b * 1280 + kt * 64 + ktok) * 256 + h * 64 + kq);
      *(u8s*)&KP[ktok * 72 + kq] = kp[0];
      *(u8s*)&KP[ktok * 72 + kq + 8] = kp[1];
      const u8s* vp = (const u8s*)(vct + (((size_t)b * 4 + h) * 64 + vd) * 1288 + kt * 64 + vtc);
      *(u8s*)&Vts[vd * 72 + vtc] = vp[0];
      *(u8s*)&Vts[vd * 72 + vtc + 8] = vp[1];
    }
    __syncthreads();
    f4 s[2][4];
#pragma unroll
    for (int mi = 0; mi < 2; mi++)
#pragma unroll
      for (int ni = 0; ni < 4; ni++) s[mi][ni] = {0.f, 0.f, 0.f, 0.f};
    bf8 aq[2][2];
#pragma unroll
    for (int ks = 0; ks < 2; ks++)
#pragma unroll
      for (int mi = 0; mi < 2; mi++)
        aq[mi][ks] = *(const bf8*)&Qs[(wv * 32 + mi * 16 + lrow) * 72 + ks * 32 + lg * 8];
#pragma unroll
    for (int ni = 0; ni < 4; ni++) {
#pragma unroll
      for (int ks = 0; ks < 2; ks++) {
        bf8 bk = *(const bf8*)&KP[(ni * 16 + lrow) * 72 + ks * 32 + lg * 8];
        s[0][ni] = MFMA16(aq[0][ks], bk, s[0][ni]);
        s[1][ni] = MFMA16(aq[1][ks], bk, s[1][ni]);
      }
    }
#pragma unroll
    for (int mi = 0; mi < 2; mi++) {
#pragma unroll
      for (int j = 0; j < 4; j++) {
        float mx = -3e38f;
#pragma unroll
        for (int ni = 0; ni < 4; ni++) {
          float v = s[mi][ni][j] * 0.125f;
          s[mi][ni][j] = v;
          mx = fmaxf(mx, v);
        }
#pragma unroll
        for (int m = 8; m >= 1; m >>= 1) mx = fmaxf(mx, __shfl_xor(mx, m));
        float nm = fmaxf(mrun[mi][j], mx);
        float alpha = __expf(mrun[mi][j] - nm);
        mrun[mi][j] = nm;
        float sum = 0.f;
#pragma unroll
        for (int ni = 0; ni < 4; ni++) {
          float p = __expf(s[mi][ni][j] - nm);
          s[mi][ni][j] = p;
          sum += p;
        }
#pragma unroll
        for (int m = 8; m >= 1; m >>= 1) sum += __shfl_xor(sum, m);
        srun[mi][j] = srun[mi][j] * alpha + sum;
#pragma unroll
        for (int ni = 0; ni < 4; ni++) o[mi][ni][j] *= alpha;
      }
    }
    __syncthreads();
#pragma unroll
    for (int mi = 0; mi < 2; mi++)
#pragma unroll
      for (int ni = 0; ni < 4; ni++)
#pragma unroll
        for (int j = 0; j < 4; j++)
          KP[(wv * 32 + mi * 16 + lg * 4 + j) * 72 + ni * 16 + lrow] = f2bf(s[mi][ni][j]);
    __syncthreads();
#pragma unroll
    for (int ks = 0; ks < 2; ks++) {
      bf8 ap0 = *(const bf8*)&KP[(wv * 32 + 0 + lrow) * 72 + ks * 32 + lg * 8];
      bf8 ap1 = *(const bf8*)&KP[(wv * 32 + 16 + lrow) * 72 + ks * 32 + lg * 8];
#pragma unroll
      for (int ni = 0; ni < 4; ni++) {
        bf8 bv = *(const bf8*)&Vts[(ni * 16 + lrow) * 72 + ks * 32 + lg * 8];
        o[0][ni] = MFMA16(ap0, bv, o[0][ni]);
        o[1][ni] = MFMA16(ap1, bv, o[1][ni]);
      }
    }
    __syncthreads();
  }
#pragma unroll
  for (int mi = 0; mi < 2; mi++)
#pragma unroll
    for (int j = 0; j < 4; j++) {
      float inv = 1.f / srun[mi][j];
      int row = qt * 128 + wv * 32 + mi * 16 + lg * 4 + j;
      float* orow = oc + ((size_t)(b * 1280 + row)) * 256 + h * 64;
#pragma unroll
      for (int ni = 0; ni < 4; ni++) orow[ni * 16 + lrow] = o[mi][ni][j] * inv;
    }
}

// ---------------------------------------------------------------- lowrank on coarse tokens
__global__ __launch_bounds__(256) void k_lowrank(const float* __restrict__ oc,
                                                 const float* __restrict__ lrd,
                                                 const float* __restrict__ lru,
                                                 float* __restrict__ oclr) {
  __shared__ float tmp[16 * 64];
  int t0 = blockIdx.x * 16;
  int tid = threadIdx.x;
  int i = tid >> 4, r4 = (tid & 15) * 4;
  f4 a = {0.f, 0.f, 0.f, 0.f};
  const float* orow = oc + (size_t)(t0 + i) * 256;
  for (int k = 0; k < 256; k++) {
    float ov = orow[k];
    const f4 w = *(const f4*)&lrd[k * 64 + r4];
    a.x += ov * w.x; a.y += ov * w.y; a.z += ov * w.z; a.w += ov * w.w;
  }
  *(f4*)&tmp[i * 64 + r4] = a;
  __syncthreads();
  int c16 = (tid & 15) * 16;
  f4 acc0 = {0.f,0.f,0.f,0.f}, acc1 = {0.f,0.f,0.f,0.f}, acc2 = {0.f,0.f,0.f,0.f}, acc3 = {0.f,0.f,0.f,0.f};
  for (int r = 0; r < 64; r++) {
    float tv = tmp[i * 64 + r];
    const f4* wr = (const f4*)&lru[r * 256 + c16];
    f4 w0 = wr[0], w1 = wr[1], w2 = wr[2], w3 = wr[3];
    acc0.x += tv * w0.x; acc0.y += tv * w0.y; acc0.z += tv * w0.z; acc0.w += tv * w0.w;
    acc1.x += tv * w1.x; acc1.y += tv * w1.y; acc1.z += tv * w1.z; acc1.w += tv * w1.w;
    acc2.x += tv * w2.x; acc2.y += tv * w2.y; acc2.z += tv * w2.z; acc2.w += tv * w2.w;
    acc3.x += tv * w3.x; acc3.y += tv * w3.y; acc3.z += tv * w3.z; acc3.w += tv * w3.w;
  }
  float* outr = oclr + (size_t)(t0 + i) * 256 + c16;
  *(f4*)&outr[0] = acc0; *(f4*)&outr[4] = acc1; *(f4*)&outr[8] = acc2; *(f4*)&outr[12] = acc3;
}

// ---------------------------------------------------------------- proj GEMM v3 (unchanged)
__global__ __launch_bounds__(256) void k_gemm_proj(const unsigned short* __restrict__ fine,
                                                   const float* __restrict__ oclr,
                                                   const unsigned short* __restrict__ wp2,
                                                   const float* __restrict__ bias,
                                                   const unsigned short* __restrict__ xin,
                                                   unsigned short* __restrict__ out1) {
  __shared__ unsigned short As[16384];
  __shared__ unsigned short Bs[8192];
  int m0 = blockIdx.x * 64;
  int tid = threadIdx.x;
  int w = tid >> 6, l = tid & 63;
  int wr = w >> 1, wc = w & 1;
  int lrow = l & 15, lg = l >> 4;

  {
    const char* gB = (const char*)wp2;
    char* lB = (char*)Bs;
    gload16(gB + tid * 16, lB + w * 1024 + l * 16);
    gload16(gB + 4096 + tid * 16, lB + 4096 + w * 1024 + l * 16);
  }
  {
    int row = tid >> 2, s = tid & 3;
    int g = s ^ ((row >> 1) & 3);
    int nrow = m0 + row;
    int z2 = nrow % D2c; int tt = nrow / D2c; int z1 = tt % D1c; tt /= D1c;
    int z0 = tt % D0c; int bb = tt / D0c;
    int ct = ((bb * 8 + z0 / 5) * 8 + z1 / 5) * 20 + z2;
    const unsigned short* fp = fine + (size_t)nrow * 256 + g * 8;
    const float* cp = oclr + (size_t)ct * 256 + g * 8;
#pragma unroll
    for (int kc = 0; kc < 8; kc++) {
      u8s fv = *(const u8s*)(fp + kc * 32);
      f4 cv0 = *(const f4*)(cp + kc * 32);
      f4 cv1 = *(const f4*)(cp + kc * 32 + 4);
      u8s t0;
      t0[0] = f2bf(bf2f(fv[0]) + cv0.x); t0[1] = f2bf(bf2f(fv[1]) + cv0.y);
      t0[2] = f2bf(bf2f(fv[2]) + cv0.z); t0[3] = f2bf(bf2f(fv[3]) + cv0.w);
      t0[4] = f2bf(bf2f(fv[4]) + cv1.x); t0[5] = f2bf(bf2f(fv[5]) + cv1.y);
      t0[6] = f2bf(bf2f(fv[6]) + cv1.z); t0[7] = f2bf(bf2f(fv[7]) + cv1.w);
      *(u8s*)&As[kc * 2048 + row * 32 + s * 8] = t0;
    }
  }
  asm volatile("s_waitcnt lgkmcnt(0)\n\ts_barrier" ::: "memory");

  int buf = 0;
  f4 acc[2][4];
  for (int nt = 0; nt < 2; nt++) {
    float bvv[4];
#pragma unroll
    for (int j = 0; j < 4; j++) bvv[j] = bias[nt * 128 + wc * 64 + j * 16 + lrow];
#pragma unroll
    for (int i = 0; i < 2; i++)
#pragma unroll
      for (int j = 0; j < 4; j++) acc[i][j] = {0.f, 0.f, 0.f, 0.f};

    for (int kc = 0; kc < 8; kc++) {
      int t = nt * 8 + kc;
      if (t + 1 < 16) {
        const char* gB = (const char*)wp2 + (size_t)(t + 1) * 8192;
        char* lB = ((char*)Bs) + (buf ^ 1) * 8192;
        gload16(gB + tid * 16, lB + w * 1024 + l * 16);
        gload16(gB + 4096 + tid * 16, lB + 4096 + w * 1024 + l * 16);
        asm volatile("s_waitcnt vmcnt(2)\n\ts_barrier" ::: "memory");
      } else {
        asm volatile("s_waitcnt vmcnt(0)\n\ts_barrier" ::: "memory");
      }
      bf8 af[2], bf_[4];
#pragma unroll
      for (int i = 0; i < 2; i++) {
        int row = wr * 32 + i * 16 + lrow;
        af[i] = *(const bf8*)&As[kc * 2048 + row * 32 + ((lg ^ ((row >> 1) & 3)) * 8)];
      }
#pragma unroll
      for (int j = 0; j < 4; j++) {
        int rowb = wc * 64 + j * 16 + lrow;
        bf_[j] = *(const bf8*)&Bs[buf * 4096 + rowb * 32 + ((lg ^ ((rowb >> 1) & 3)) * 8)];
      }
#pragma unroll
      for (int i = 0; i < 2; i++)
#pragma unroll
        for (int j = 0; j < 4; j++) acc[i][j] = MFMA16(af[i], bf_[j], acc[i][j]);
      asm volatile("s_barrier" ::: "memory");
      buf ^= 1;
    }

    unsigned short* Cs = &Bs[(buf ^ 1) * 4096];
    int crow = tid >> 3, cseg = tid & 7;
#pragma unroll
    for (int h = 0; h < 2; h++) {
      if (wr == h) {
#pragma unroll
        for (int i = 0; i < 2; i++)
#pragma unroll
          for (int j = 0; j < 4; j++)
#pragma unroll
            for (int r = 0; r < 4; r++)
              Cs[(i * 16 + lg * 4 + r) * 128 + wc * 64 + j * 16 + lrow] =
                  f2bf(acc[i][j][r] + bvv[j]);
      }
      asm volatile("s_waitcnt lgkmcnt(0)\n\ts_barrier" ::: "memory");
      {
        u8s v0 = *(const u8s*)&Cs[crow * 128 + cseg * 16];
        u8s v1 = *(const u8s*)&Cs[crow * 128 + cseg * 16 + 8];
        const unsigned short* xrow = xin + (size_t)(m0 + h * 32 + crow) * 256 + nt * 128 + cseg * 16;
        u8s x0 = *(const u8s*)xrow;
        u8s x1 = *(const u8s*)(xrow + 8);
        u8s o0, o1;
#pragma unroll
        for (int e = 0; e < 8; e++) {
          o0[e] = f2bf(bf2f(v0[e]) + bf2f(x0[e]));
          o1[e] = f2bf(bf2f(v1[e]) + bf2f(x1[e]));
        }
        unsigned short* orow = out1 + (size_t)(m0 + h * 32 + crow) * 256 + nt * 128 + cseg * 16;
        *(u8s*)orow = o0;
        *(u8s*)(orow + 8) = o1;
      }
      asm volatile("s_waitcnt lgkmcnt(0)\n\ts_barrier" ::: "memory");
    }
  }
}

// ---------------------------------------------------------------- post conv: wave=column 4ch/lane, zero-page, 2-deep prefetch,
// fused rmsnorm (wave-local shuffle) + residual
__global__ __launch_bounds__(256) void k_convpost(const unsigned short* __restrict__ o1,
                                                  const float* __restrict__ dw,
                                                  const unsigned short* __restrict__ zpad,
                                                  const float* __restrict__ x,
                                                  const float* __restrict__ anw,
                                                  float* __restrict__ outp) {
  __shared__ float wl[6912];
  for (int i = threadIdx.x; i < 6912; i += 256) wl[i] = dw[i];
  __syncthreads();
  int wv = threadIdx.x >> 6, ln = threadIdx.x & 63;
  int col = blockIdx.x * 4 + wv;
  int z1 = col % D1c; int t = col / D1c; int z0 = t % D0c; int b = t / D0c;
  int c0 = ln * 4;

  const unsigned short* base[9];
#pragma unroll
  for (int c = 0; c < 9; c++) {
    int dy = c / 3 - 1, dx = c % 3 - 1;
    int y0 = z0 + dy, y1 = z1 + dx;
    bool valid = ((unsigned)y0 < (unsigned)D0c) && ((unsigned)y1 < (unsigned)D1c);
    base[c] = valid ? (o1 + ((size_t)((b * D0c + y0) * D1c + y1) * D2c) * 256 + c0)
                    : (zpad + c0);
  }
  f4 a0 = {0.f,0.f,0.f,0.f}, a1 = {0.f,0.f,0.f,0.f}, a2 = {0.f,0.f,0.f,0.f};
  ushort4 n0[9], n1[9];
  CONV_LOAD(n0, 0);
  CONV_LOAD(n1, 1);
  const f4 wv4 = *(const f4*)(anw + c0);
  const float* xp = x + ((size_t)col * D2c) * 256 + c0;
  float* op = outp + ((size_t)col * D2c) * 256 + c0;

#define POST_STORE()                                                          \
  do {                                                                        \
    float ss = a0.x * a0.x + a0.y * a0.y + a0.z * a0.z + a0.w * a0.w;         \
    _Pragma("unroll") for (int m = 32; m >= 1; m >>= 1)                       \
        ss += __shfl_xor(ss, m);                                              \
    float rs = rsqrtf(ss * (1.f / 256.f) + 1e-6f);                            \
    f4 xv = *(const f4*)xp;                                                   \
    f4 res;                                                                   \
    res.x = xv.x + a0.x * wv4.x * rs;                                         \
    res.y = xv.y + a0.y * wv4.y * rs;                                         \
    res.z = xv.z + a0.z * wv4.z * rs;                                         \
    res.w = xv.w + a0.w * wv4.w * rs;                                         \
    *(f4*)op = res;                                                           \
    xp += 256; op += 256;                                                     \
  } while (0)

  CONV_CONSUME(n0);
  CONV_SHIFT();
  CONV_LOAD(n0, 2);
  CONV_CONSUME(n1);
  POST_STORE();
  CONV_SHIFT();
  CONV_LOAD(n1, 3);

  for (int z = 2; z < 20; z += 2) {
    CONV_CONSUME(n0);
    POST_STORE();
    CONV_SHIFT();
    int r2 = (z + 2 > 19) ? 19 : (z + 2);
    CONV_LOAD(n0, r2);

    CONV_CONSUME(n1);
    POST_STORE();
    CONV_SHIFT();
    int r3 = (z + 3 > 19) ? 19 : (z + 3);
    CONV_LOAD(n1, r3);
  }
  POST_STORE();
#undef POST_STORE
}

// ---------------------------------------------------------------- launch
extern "C" void kernel_launch(void* const* d_in, const int* in_sizes, int n_in,
                              void* d_out, int out_size, void* d_ws, size_t ws_size,
                              hipStream_t stream) {
  const float* x          = (const float*)d_in[0];
  const float* norm1_w    = (const float*)d_in[1];
  const float* attn_norm_w= (const float*)d_in[2];
  const float* qkv_w      = (const float*)d_in[3];
  const float* qkv_b      = (const float*)d_in[4];
  const float* proj_w     = (const float*)d_in[5];
  const float* proj_b     = (const float*)d_in[6];
  const float* dw_pre     = (const float*)d_in[7];
  const float* dw_post    = (const float*)d_in[8];
  const float* lr_down    = (const float*)d_in[9];
  const float* lr_up      = (const float*)d_in[10];
  float* outp = (float*)d_out;

  unsigned char* w = (unsigned char*)d_ws;
  size_t off = 0;
  unsigned short* xn   = (unsigned short*)(w + off); off += 65536000ULL;   // reused as `fine`
  unsigned short* xin  = (unsigned short*)(w + off); off += 65536000ULL;
  unsigned short* qkv  = (unsigned short*)(w + off); off += 196608000ULL;
  unsigned short* out1 = (unsigned short*)(w + off); off += 65536000ULL;
  unsigned short* qc   = (unsigned short*)(w + off); off += 2621440ULL;
  unsigned short* kc   = (unsigned short*)(w + off); off += 2621440ULL;
  unsigned short* vct  = (unsigned short*)(w + off); off += 2637824ULL;
  float* oc            = (float*)(w + off);          off += 5242880ULL;
  float* oclr          = (float*)(w + off);          off += 5242880ULL;
  unsigned short* wq   = (unsigned short*)(w + off); off += 393216ULL;
  unsigned short* wp   = (unsigned short*)(w + off); off += 131072ULL;
  unsigned short* zpad = (unsigned short*)(w + off); off += 12288ULL;
  unsigned short* fine = xn;  // xn dead after k_convpre

  k_prepw<<<1025, 256, 0, stream>>>(qkv_w, proj_w, wq, wp, zpad);
  k_rms1<<<32000, 256, 0, stream>>>(x, norm1_w, xn);
  k_convpre<<<1600, 256, 0, stream>>>(xn, dw_pre, zpad, xin);
  k_gemm_qkv<<<1000, 512, 0, stream>>>(xin, wq, qkv_b, qkv);
  k_fineattn<<<4096, 256, 0, stream>>>(qkv, fine);
  k_pool<<<5120, 128, 0, stream>>>(qkv, qc, kc, vct);
  k_coarse<<<dim3(10, 16), 256, 0, stream>>>(qc, kc, vct, oc);
  k_lowrank<<<320, 256, 0, stream>>>(oc, lr_down, lr_up, oclr);
  k_gemm_proj<<<2000, 256, 0, stream>>>(fine, oclr, wp, proj_b, xin, out1);
  k_convpost<<<1600, 256, 0, stream>>>(out1, dw_post, zpad, x, attn_norm_w, outp);
}